// Round 3
// baseline (115.166 us; speedup 1.0000x reference)
//
#include <hip/hip_runtime.h>
#include <math.h>

#define HH 512
#define WW 512
#define NB 8
#define NACC 72     // 45 sym AtA + 27 Atb
#define CHUNKS 256  // 2-row chunks per batch = grid.x

// Per-row load bundle: 7 float4 + 2 edge scalars (30 floats).
struct RowData {
    float4 cen, up, dn, i0, i1, i2, al;
    float  lsc, rsc;
};

// ---------------------------------------------------------------------------
// Kernel 1: per-pixel SH basis + normal-equation accumulation.
//
// THIS ROUND (occupancy): 128-thread blocks, 2 rows/block, CHUNKS=256 ->
// grid (256,8)=2048 blocks. __launch_bounds__(128,3): 3 waves/EU target ->
// VGPR cap 512/3=170 (current ~150 fits, no spill) -> 6 blocks/CU resident
// = 12 waves/CU vs the old hard 8 (the old 512-block grid could never
// exceed 2 blocks/CU). R2's bigger-than-predicted tail win showed accum is
// latency/issue-bound, so +50% TLP is the lever. XCD-chunked bijective
// swizzle on blockIdx.x (2048%8==0) keeps adjacent 2-row chunks on one
// XCD L2 so the now-2x depth-row overlap re-reads hit L2.
//
// History (load-bearing):
//   - no launch_bounds -> 64-VGPR cap -> acc[72] spills, 249 MB HBM, 130us.
//   - (256,3) -> compiler targeted 6 waves/EU, 84 VGPR, spill, 145us total.
//   - (256,2): 150 VGPR, accum ~13-15us. R2 select-halving tail: -5.2us.
// Per-pixel arithmetic identical since R0 (absmax stable at 0.0625 across
// two reduction-order changes -> threshold has margin).
// ---------------------------------------------------------------------------
__global__ __launch_bounds__(128, 3)
void accum_kernel(const float* __restrict__ img,   // (B,3,H,W)
                  const float* __restrict__ dep,   // (B,1,H,W)
                  const float* __restrict__ alb,   // (B,3,H,W)
                  float* __restrict__ ws)          // (NB,CHUNKS,72) partials
{
    const int b   = blockIdx.y;
    const int tid = threadIdx.x;
    const int tx  = tid;                 // 0..127 -> 4-px group
    // XCD-chunked swizzle: linear wg id % 8 = blockIdx.x % 8 (gridDim.x=256,
    // 256*blockIdx.y % 8 == 0). chunk = (bx%8)*32 + bx/8 gives XCD x the
    // contiguous chunk range [32x, 32x+32) -> neighbor chunks share L2.
    const int bx    = blockIdx.x;
    const int chunk = ((bx & 7) << 5) | (bx >> 3);
    const int y0  = chunk * 2;
    const int x0  = tx * 4;

    // SH constants (double math, constant-folded; PI=3.14159 as reference)
    const float c0 = (float)(3.14159 * sqrt(1.0 / (4.0 * 3.14159)));
    const float c1 = (float)(2.0 * 3.14159 / 3.0 * sqrt(3.0 / (4.0 * 3.14159)));
    const float c2 = (float)(3.14159 / 4.0 * 0.5 * sqrt(5.0 / (4.0 * 3.14159)));
    const float c3 = (float)(3.14159 / 4.0 * 3.0 * sqrt(5.0 / (12.0 * 3.14159)));
    const float c4 = (float)(3.14159 / 4.0 * 3.0 * sqrt(5.0 / (48.0 * 3.14159)));

    float acc[NACC];
#pragma unroll
    for (int i = 0; i < NACC; ++i) acc[i] = 0.0f;

    const float* depb  = dep + (size_t)b * HH * WW;
    const float* img0b = img + (size_t)(b * 3 + 0) * HH * WW;
    const float* img1b = img + (size_t)(b * 3 + 1) * HH * WW;
    const float* img2b = img + (size_t)(b * 3 + 2) * HH * WW;
    const float* alb2b = alb + (size_t)(b * 3 + 2) * HH * WW;

    // fx for x0-1 .. x0+4 (same for every row this thread touches)
    float fxv[6];
#pragma unroll
    for (int k = 0; k < 6; ++k)
        fxv[k] = ((float)(x0 - 1 + k) - 256.0f) / 608.365f;

    // row indices + validity for the 2 passes
    int  yv[2];
    bool vr[2];
#pragma unroll
    for (int p = 0; p < 2; ++p) {
        const int y = y0 + p;
        vr[p] = (y >= 1) && (y < HH - 1);
        yv[p] = vr[p] ? y : 1;            // clamp: loads stay in-bounds
    }

    auto load_row = [&](int y) -> RowData {
        RowData r;
        const int row = y * WW + x0;
        r.cen = *reinterpret_cast<const float4*>(depb + row);
        r.up  = *reinterpret_cast<const float4*>(depb + row - WW);
        r.dn  = *reinterpret_cast<const float4*>(depb + row + WW);
        r.lsc = depb[row - (tx == 0 ? 0 : 1)];
        r.rsc = depb[row + 4];
        r.i0  = *reinterpret_cast<const float4*>(img0b + row);
        r.i1  = *reinterpret_cast<const float4*>(img1b + row);
        r.i2  = *reinterpret_cast<const float4*>(img2b + row);
        r.al  = *reinterpret_cast<const float4*>(alb2b + row);
        return r;
    };

    RowData cur = load_row(yv[0]);

#pragma unroll
    for (int pass = 0; pass < 2; ++pass) {
        RowData nxt;
        if (pass < 1) nxt = load_row(yv[pass + 1]);   // prefetch next pass

        if (vr[pass]) {
            const int y = yv[pass];
            const float fy  = ((float)y       - 256.0f) / 608.365f;
            const float fyd = ((float)(y + 1) - 256.0f) / 608.365f;
            const float fyu = ((float)(y - 1) - 256.0f) / 608.365f;

            // depth transform (d+1)/2
            float cA[4] = {(cur.cen.x + 1.0f) * 0.5f, (cur.cen.y + 1.0f) * 0.5f,
                           (cur.cen.z + 1.0f) * 0.5f, (cur.cen.w + 1.0f) * 0.5f};
            float uA[4] = {(cur.up.x + 1.0f) * 0.5f, (cur.up.y + 1.0f) * 0.5f,
                           (cur.up.z + 1.0f) * 0.5f, (cur.up.w + 1.0f) * 0.5f};
            float dA[4] = {(cur.dn.x + 1.0f) * 0.5f, (cur.dn.y + 1.0f) * 0.5f,
                           (cur.dn.z + 1.0f) * 0.5f, (cur.dn.w + 1.0f) * 0.5f};
            const float lT = (cur.lsc + 1.0f) * 0.5f;
            const float rT = (cur.rsc + 1.0f) * 0.5f;
            const float g0[4] = {cur.i0.x, cur.i0.y, cur.i0.z, cur.i0.w};
            const float g1[4] = {cur.i1.x, cur.i1.y, cur.i1.z, cur.i1.w};
            const float g2[4] = {cur.i2.x, cur.i2.y, cur.i2.z, cur.i2.w};
            const float aA[4] = {cur.al.x, cur.al.y, cur.al.z, cur.al.w};

#pragma unroll
            for (int p = 0; p < 4; ++p) {
                const bool valid = !((p == 0 && tx == 0) || (p == 3 && tx == 127));

                const float dc = cA[p];
                const float dl = (p == 0) ? lT : cA[(p == 0) ? 0 : p - 1];
                const float dr = (p == 3) ? rT : cA[(p == 3) ? 3 : p + 1];
                const float du = uA[p];
                const float dd = dA[p];

                const float fx  = fxv[p + 1];
                const float fxl = fxv[p];
                const float fxr = fxv[p + 2];

                // 3D points
                const float pcx = fx  * dc, pcy = fy  * dc;
                const float prx = fxr * dr, pry = fy  * dr;
                const float plx = fxl * dl, ply = fy  * dl;
                const float pdx = fx  * dd, pdy = fyd * dd;
                const float pux = fx  * du, puy = fyu * du;

                // vw = pc-pr ; vs = pd-pc ; ve = pc-pl ; vn = pu-pc
                const float vwx = pcx - prx, vwy = pcy - pry, vwz = dc - dr;
                const float vsx = pdx - pcx, vsy = pdy - pcy, vsz = dd - dc;
                const float vex = pcx - plx, vey = pcy - ply, vez = dc - dl;
                const float vnx = pux - pcx, vny = puy - pcy, vnz = du - dc;

                // normal = cross(vw,vs) + cross(ve,vn)
                const float nx = (vwy * vsz - vwz * vsy) + (vey * vnz - vez * vny);
                const float ny = (vwz * vsx - vwx * vsz) + (vez * vnx - vex * vnz);
                const float nz = (vwx * vsy - vwy * vsx) + (vex * vny - vey * vnx);

                const float nn   = nx * nx + ny * ny + nz * nz;
                const float mag  = sqrtf(nn);
                const float den  = valid ? mag : 1.0f;   // avoid NaN on dead px
                const float invm = 1.0f / den;
                const float uxn = nx * invm, uyn = ny * invm, uzn = nz * invm;
                const float x2 = uxn * uxn, y2 = uyn * uyn, z2 = uzn * uzn;

                const float N0 = c0 * mag;
                const float N1 = c1 * nz;
                const float N2 = c1 * nx;
                const float N3 = c1 * ny;
                const float N4 = c2 * (2.0f * z2 - x2 - y2) * mag;
                const float N5 = c3 * (uxn * uzn) * mag;
                const float N6 = c3 * (uyn * uzn) * mag;
                const float N7 = c4 * (x2 - y2) * mag;
                const float N8 = c3 * (uxn * uyn) * mag;

                // img = (in+1)/2 ; mask = img0 != 0 ; kill dead px via vf
                const float vf = valid ? 1.0f : 0.0f;
                const float i0 = (g0[p] + 1.0f) * 0.5f;
                const float i1 = (g1[p] + 1.0f) * 0.5f;
                const float i2 = (g2[p] + 1.0f) * 0.5f;
                const float m  = ((i0 != 0.0f) ? 1.0f : 0.0f) * vf;
                const float b0 = i0 * m, b1 = i1 * m, b2 = i2 * m;
                const float rho = aA[p] * m;

                const float A[9] = {N0 * rho, N1 * rho, N2 * rho, N3 * rho,
                                    N4 * rho, N5 * rho, N6 * rho, N7 * rho,
                                    N8 * rho};

                int k = 0;
#pragma unroll
                for (int i = 0; i < 9; ++i)
#pragma unroll
                    for (int j = i; j < 9; ++j) {
                        acc[k] = fmaf(A[i], A[j], acc[k]);
                        ++k;
                    }
#pragma unroll
                for (int i = 0; i < 9; ++i) {
                    acc[45 + i] = fmaf(b0, A[i], acc[45 + i]);
                    acc[54 + i] = fmaf(b1, A[i], acc[54 + i]);
                    acc[63 + i] = fmaf(b2, A[i], acc[63 + i]);
                }
            }
        }
        cur = nxt;
    }

    // ---- select-halving wave reduction (R2, -5.2us vs full butterfly) ----
    // xor 8/16/32 halve live values 72->36->18->9 (keep/send pairwise,
    // compile-time indices only), then xor 1/2/4 finish the 9 wave sums.
    const int lane = tid & 63;
    const int wave = tid >> 6;
    const bool b3 = (lane & 8)  != 0;
    const bool b4 = (lane & 16) != 0;
    const bool b5 = (lane & 32) != 0;

    float r36[36];
#pragma unroll
    for (int j = 0; j < 36; ++j) {
        const float keep = b3 ? acc[2 * j + 1] : acc[2 * j];
        const float send = b3 ? acc[2 * j]     : acc[2 * j + 1];
        r36[j] = keep + __shfl_xor(send, 8, 64);
    }
    float r18[18];
#pragma unroll
    for (int j = 0; j < 18; ++j) {
        const float keep = b4 ? r36[2 * j + 1] : r36[2 * j];
        const float send = b4 ? r36[2 * j]     : r36[2 * j + 1];
        r18[j] = keep + __shfl_xor(send, 16, 64);
    }
    // Lane now owns orig indices {8j + g}, g=(lane>>3)&7.
    float r9[9];
#pragma unroll
    for (int j = 0; j < 9; ++j) {
        const float keep = b5 ? r18[2 * j + 1] : r18[2 * j];
        const float send = b5 ? r18[2 * j]     : r18[2 * j + 1];
        r9[j] = keep + __shfl_xor(send, 32, 64);
    }
#pragma unroll
    for (int j = 0; j < 9; ++j) {
        float v = r9[j];
        v += __shfl_xor(v, 1, 64);
        v += __shfl_xor(v, 2, 64);
        v += __shfl_xor(v, 4, 64);
        r9[j] = v;
    }

    // one publisher lane per ownership group g: lanes 0,8,...,56
    __shared__ float red[2][NACC];
    const int g = (lane >> 3) & 7;
    if ((lane & 7) == 0) {
#pragma unroll
        for (int j = 0; j < 9; ++j) red[wave][8 * j + g] = r9[j];
    }
    __syncthreads();
    if (tid < NACC) {
        const float s = red[0][tid] + red[1][tid];
        ws[((size_t)b * CHUNKS + chunk) * NACC + tid] = s;  // no atomics
    }
}

// ---------------------------------------------------------------------------
// Kernel 2: reduce the 256 per-chunk partials, then 9x9 solve w/ 3 RHS.
// Parallel elimination (R1, -3.8us vs serial t==0 version):
//   - chunk-sum: 72 threads in parallel,
//   - elimination: 108 threads own one M[i][j] element; per pivot step
//     {t0 pivot-scan -> 12-thread row swap -> 9-thread multiplier calc ->
//      108-thread rank-1 update}, barriers between phases.
//   - back-substitution: 3 RHS on 3 parallel threads.
// One block per batch. Output S is (B,3,9).
// ---------------------------------------------------------------------------
__global__ __launch_bounds__(128)
void solve_kernel(const float* __restrict__ ws, float* __restrict__ out)
{
    __shared__ float sums[NACC];
    __shared__ float M[9][12];
    __shared__ float fs[9];
    __shared__ int piv_s;
    const int b = blockIdx.x;
    const int t = threadIdx.x;

    // parallel reduction of the 256 per-chunk partials
    if (t < NACC) {
        float s = 0.0f;
        const float* p = ws + (size_t)b * CHUNKS * NACC + t;
#pragma unroll 16
        for (int c = 0; c < CHUNKS; ++c) s += p[(size_t)c * NACC];
        sums[t] = s;
    }
    __syncthreads();

    // scatter into the 9x12 augmented system, one element per thread
    const int i  = t / 12;
    const int j  = t % 12;
    const bool on = (t < 108);
    if (on) {
        float v;
        if (j < 9) {
            const int lo = (i < j) ? i : j;
            const int hi = (i < j) ? j : i;
            const int k  = lo * 9 - lo * (lo - 1) / 2 + (hi - lo);
            v = sums[k];                      // symmetric AtA
        } else {
            v = sums[45 + (j - 9) * 9 + i];   // Atb, RHS c = j-9
        }
        M[i][j] = v;
    }
    __syncthreads();

    // forward elimination with partial pivoting, parallel over elements
    for (int kk = 0; kk < 9; ++kk) {
        if (t == 0) {
            int piv = kk;
            float best = fabsf(M[kk][kk]);
            for (int r = kk + 1; r < 9; ++r) {
                const float av = fabsf(M[r][kk]);
                if (av > best) { best = av; piv = r; }
            }
            piv_s = piv;
        }
        __syncthreads();
        const int piv = piv_s;
        if (piv != kk && t < 12) {
            const float tmp = M[kk][t];
            M[kk][t] = M[piv][t];
            M[piv][t] = tmp;
        }
        __syncthreads();
        if (t > kk && t < 9) fs[t] = M[t][kk] / M[kk][kk];
        __syncthreads();
        if (on && i > kk) M[i][j] -= fs[i] * M[kk][j];
        __syncthreads();
    }

    // back substitution: 3 RHS in parallel (one thread each)
    if (t < 3) {
        float sol[9];
        for (int kk = 8; kk >= 0; --kk) {
            float v = M[kk][9 + t];
            for (int jj = kk + 1; jj < 9; ++jj) v -= M[kk][jj] * sol[jj];
            sol[kk] = v / M[kk][kk];
        }
        for (int kk = 0; kk < 9; ++kk)
            out[(b * 3 + t) * 9 + kk] = sol[kk];
    }
}

extern "C" void kernel_launch(void* const* d_in, const int* in_sizes, int n_in,
                              void* d_out, int out_size, void* d_ws, size_t ws_size,
                              hipStream_t stream) {
    const float* img = (const float*)d_in[0];   // input_img  (8,3,512,512)
    const float* dep = (const float*)d_in[1];   // depth_target (8,1,512,512)
    const float* alb = (const float*)d_in[2];   // albedo (8,3,512,512)
    float* out = (float*)d_out;                 // S (8,3,9)
    float* ws  = (float*)d_ws;                  // 8*256*72 partial floats

    dim3 grid(CHUNKS, NB);
    accum_kernel<<<grid, 128, 0, stream>>>(img, dep, alb, ws);
    solve_kernel<<<NB, 128, 0, stream>>>(ws, out);
}

// Round 4
// 102.783 us; speedup vs baseline: 1.1205x; 1.1205x over previous
//
#include <hip/hip_runtime.h>
#include <math.h>

#define HH 512
#define WW 512
#define NB 8
#define NACC 72     // 45 sym AtA + 27 Atb
#define CHUNKS 64   // row-chunks per batch = grid.x

// Per-row load bundle: 7 float4 + 2 edge scalars (30 floats).
struct RowData {
    float4 cen, up, dn, i0, i1, i2, al;
    float  lsc, rsc;
};

// ---------------------------------------------------------------------------
// Kernel 1: per-pixel SH basis + normal-equation accumulation.
// Grid: (CHUNKS, NB) x 256 threads; tx = tid&127 -> 4-px group (aligned
// float4), ty = tid>>7 -> one of 2 rows per pass, 4 passes = 8 rows/block.
//
// STRUCTURE IS LOAD-BEARING (session history):
//   - no launch_bounds -> 64-VGPR cap -> acc[72] spills, 249 MB HBM, 130us.
//   - (256,3) -> 84 VGPR, AGPR-spill + serial tail -> 145us total.
//   - (256,2): ~150 VGPR, no spill. R2 select-halving tail: -5.2us (101us).
//   - R3 FALSIFIED the occupancy theory: 128-thr/2-row/CHUNKS=256 blocks
//     (6 blocks/CU resident vs 2) regressed to 115us. 4x more per-block
//     epilogues + setup amortized over half the pixels dominates any TLP
//     gain. Do NOT shrink the per-block pixel count; 16 px/thread main
//     loop vs one ~306-op tail is the winning ratio.
// Per-pixel arithmetic identical since R0 (absmax stable at 0.0625).
// ---------------------------------------------------------------------------
__global__ __launch_bounds__(256, 2)
void accum_kernel(const float* __restrict__ img,   // (B,3,H,W)
                  const float* __restrict__ dep,   // (B,1,H,W)
                  const float* __restrict__ alb,   // (B,3,H,W)
                  float* __restrict__ ws)          // (NB,CHUNKS,72) partials
{
    const int b   = blockIdx.y;
    const int tid = threadIdx.x;
    const int tx  = tid & 127;
    const int ty  = tid >> 7;
    const int y0  = blockIdx.x * 8;
    const int x0  = tx * 4;

    // SH constants (double math, constant-folded; PI=3.14159 as reference)
    const float c0 = (float)(3.14159 * sqrt(1.0 / (4.0 * 3.14159)));
    const float c1 = (float)(2.0 * 3.14159 / 3.0 * sqrt(3.0 / (4.0 * 3.14159)));
    const float c2 = (float)(3.14159 / 4.0 * 0.5 * sqrt(5.0 / (4.0 * 3.14159)));
    const float c3 = (float)(3.14159 / 4.0 * 3.0 * sqrt(5.0 / (12.0 * 3.14159)));
    const float c4 = (float)(3.14159 / 4.0 * 3.0 * sqrt(5.0 / (48.0 * 3.14159)));

    float acc[NACC];
#pragma unroll
    for (int i = 0; i < NACC; ++i) acc[i] = 0.0f;

    const float* depb  = dep + (size_t)b * HH * WW;
    const float* img0b = img + (size_t)(b * 3 + 0) * HH * WW;
    const float* img1b = img + (size_t)(b * 3 + 1) * HH * WW;
    const float* img2b = img + (size_t)(b * 3 + 2) * HH * WW;
    const float* alb2b = alb + (size_t)(b * 3 + 2) * HH * WW;

    // fx for x0-1 .. x0+4 (same for every row this thread touches)
    float fxv[6];
#pragma unroll
    for (int k = 0; k < 6; ++k)
        fxv[k] = ((float)(x0 - 1 + k) - 256.0f) / 608.365f;

    // row indices + validity for the 4 passes
    int  yv[4];
    bool vr[4];
#pragma unroll
    for (int p = 0; p < 4; ++p) {
        const int y = y0 + p * 2 + ty;
        vr[p] = (y >= 1) && (y < HH - 1);
        yv[p] = vr[p] ? y : 1;            // clamp: loads stay in-bounds
    }

    auto load_row = [&](int y) -> RowData {
        RowData r;
        const int row = y * WW + x0;
        r.cen = *reinterpret_cast<const float4*>(depb + row);
        r.up  = *reinterpret_cast<const float4*>(depb + row - WW);
        r.dn  = *reinterpret_cast<const float4*>(depb + row + WW);
        r.lsc = depb[row - (tx == 0 ? 0 : 1)];
        r.rsc = depb[row + 4];
        r.i0  = *reinterpret_cast<const float4*>(img0b + row);
        r.i1  = *reinterpret_cast<const float4*>(img1b + row);
        r.i2  = *reinterpret_cast<const float4*>(img2b + row);
        r.al  = *reinterpret_cast<const float4*>(alb2b + row);
        return r;
    };

    RowData cur = load_row(yv[0]);

#pragma unroll
    for (int pass = 0; pass < 4; ++pass) {
        RowData nxt;
        if (pass < 3) nxt = load_row(yv[pass + 1]);   // prefetch next pass

        if (vr[pass]) {
            const int y = yv[pass];
            const float fy  = ((float)y       - 256.0f) / 608.365f;
            const float fyd = ((float)(y + 1) - 256.0f) / 608.365f;
            const float fyu = ((float)(y - 1) - 256.0f) / 608.365f;

            // depth transform (d+1)/2
            float cA[4] = {(cur.cen.x + 1.0f) * 0.5f, (cur.cen.y + 1.0f) * 0.5f,
                           (cur.cen.z + 1.0f) * 0.5f, (cur.cen.w + 1.0f) * 0.5f};
            float uA[4] = {(cur.up.x + 1.0f) * 0.5f, (cur.up.y + 1.0f) * 0.5f,
                           (cur.up.z + 1.0f) * 0.5f, (cur.up.w + 1.0f) * 0.5f};
            float dA[4] = {(cur.dn.x + 1.0f) * 0.5f, (cur.dn.y + 1.0f) * 0.5f,
                           (cur.dn.z + 1.0f) * 0.5f, (cur.dn.w + 1.0f) * 0.5f};
            const float lT = (cur.lsc + 1.0f) * 0.5f;
            const float rT = (cur.rsc + 1.0f) * 0.5f;
            const float g0[4] = {cur.i0.x, cur.i0.y, cur.i0.z, cur.i0.w};
            const float g1[4] = {cur.i1.x, cur.i1.y, cur.i1.z, cur.i1.w};
            const float g2[4] = {cur.i2.x, cur.i2.y, cur.i2.z, cur.i2.w};
            const float aA[4] = {cur.al.x, cur.al.y, cur.al.z, cur.al.w};

#pragma unroll
            for (int p = 0; p < 4; ++p) {
                const bool valid = !((p == 0 && tx == 0) || (p == 3 && tx == 127));

                const float dc = cA[p];
                const float dl = (p == 0) ? lT : cA[(p == 0) ? 0 : p - 1];
                const float dr = (p == 3) ? rT : cA[(p == 3) ? 3 : p + 1];
                const float du = uA[p];
                const float dd = dA[p];

                const float fx  = fxv[p + 1];
                const float fxl = fxv[p];
                const float fxr = fxv[p + 2];

                // 3D points
                const float pcx = fx  * dc, pcy = fy  * dc;
                const float prx = fxr * dr, pry = fy  * dr;
                const float plx = fxl * dl, ply = fy  * dl;
                const float pdx = fx  * dd, pdy = fyd * dd;
                const float pux = fx  * du, puy = fyu * du;

                // vw = pc-pr ; vs = pd-pc ; ve = pc-pl ; vn = pu-pc
                const float vwx = pcx - prx, vwy = pcy - pry, vwz = dc - dr;
                const float vsx = pdx - pcx, vsy = pdy - pcy, vsz = dd - dc;
                const float vex = pcx - plx, vey = pcy - ply, vez = dc - dl;
                const float vnx = pux - pcx, vny = puy - pcy, vnz = du - dc;

                // normal = cross(vw,vs) + cross(ve,vn)
                const float nx = (vwy * vsz - vwz * vsy) + (vey * vnz - vez * vny);
                const float ny = (vwz * vsx - vwx * vsz) + (vez * vnx - vex * vnz);
                const float nz = (vwx * vsy - vwy * vsx) + (vex * vny - vey * vnx);

                const float nn   = nx * nx + ny * ny + nz * nz;
                const float mag  = sqrtf(nn);
                const float den  = valid ? mag : 1.0f;   // avoid NaN on dead px
                const float invm = 1.0f / den;
                const float uxn = nx * invm, uyn = ny * invm, uzn = nz * invm;
                const float x2 = uxn * uxn, y2 = uyn * uyn, z2 = uzn * uzn;

                const float N0 = c0 * mag;
                const float N1 = c1 * nz;
                const float N2 = c1 * nx;
                const float N3 = c1 * ny;
                const float N4 = c2 * (2.0f * z2 - x2 - y2) * mag;
                const float N5 = c3 * (uxn * uzn) * mag;
                const float N6 = c3 * (uyn * uzn) * mag;
                const float N7 = c4 * (x2 - y2) * mag;
                const float N8 = c3 * (uxn * uyn) * mag;

                // img = (in+1)/2 ; mask = img0 != 0 ; kill dead px via vf
                const float vf = valid ? 1.0f : 0.0f;
                const float i0 = (g0[p] + 1.0f) * 0.5f;
                const float i1 = (g1[p] + 1.0f) * 0.5f;
                const float i2 = (g2[p] + 1.0f) * 0.5f;
                const float m  = ((i0 != 0.0f) ? 1.0f : 0.0f) * vf;
                const float b0 = i0 * m, b1 = i1 * m, b2 = i2 * m;
                const float rho = aA[p] * m;

                const float A[9] = {N0 * rho, N1 * rho, N2 * rho, N3 * rho,
                                    N4 * rho, N5 * rho, N6 * rho, N7 * rho,
                                    N8 * rho};

                int k = 0;
#pragma unroll
                for (int i = 0; i < 9; ++i)
#pragma unroll
                    for (int j = i; j < 9; ++j) {
                        acc[k] = fmaf(A[i], A[j], acc[k]);
                        ++k;
                    }
#pragma unroll
                for (int i = 0; i < 9; ++i) {
                    acc[45 + i] = fmaf(b0, A[i], acc[45 + i]);
                    acc[54 + i] = fmaf(b1, A[i], acc[54 + i]);
                    acc[63 + i] = fmaf(b2, A[i], acc[63 + i]);
                }
            }
        }
        cur = nxt;
    }

    // ---- select-halving wave reduction (R2, -5.2us vs full butterfly) ----
    // xor 8/16/32 halve live values 72->36->18->9 (keep/send pairwise,
    // compile-time indices only), then xor 1/2/4 finish the 9 wave sums.
    const int lane = tid & 63;
    const int wave = tid >> 6;
    const bool b3 = (lane & 8)  != 0;
    const bool b4 = (lane & 16) != 0;
    const bool b5 = (lane & 32) != 0;

    float r36[36];
#pragma unroll
    for (int j = 0; j < 36; ++j) {
        const float keep = b3 ? acc[2 * j + 1] : acc[2 * j];
        const float send = b3 ? acc[2 * j]     : acc[2 * j + 1];
        r36[j] = keep + __shfl_xor(send, 8, 64);
    }
    float r18[18];
#pragma unroll
    for (int j = 0; j < 18; ++j) {
        const float keep = b4 ? r36[2 * j + 1] : r36[2 * j];
        const float send = b4 ? r36[2 * j]     : r36[2 * j + 1];
        r18[j] = keep + __shfl_xor(send, 16, 64);
    }
    // Lane now owns orig indices {8j + g}, g=(lane>>3)&7.
    float r9[9];
#pragma unroll
    for (int j = 0; j < 9; ++j) {
        const float keep = b5 ? r18[2 * j + 1] : r18[2 * j];
        const float send = b5 ? r18[2 * j]     : r18[2 * j + 1];
        r9[j] = keep + __shfl_xor(send, 32, 64);
    }
#pragma unroll
    for (int j = 0; j < 9; ++j) {
        float v = r9[j];
        v += __shfl_xor(v, 1, 64);
        v += __shfl_xor(v, 2, 64);
        v += __shfl_xor(v, 4, 64);
        r9[j] = v;
    }

    // one publisher lane per ownership group g: lanes 0,8,...,56
    __shared__ float red[4][NACC];
    const int g = (lane >> 3) & 7;
    if ((lane & 7) == 0) {
#pragma unroll
        for (int j = 0; j < 9; ++j) red[wave][8 * j + g] = r9[j];
    }
    __syncthreads();
    if (tid < NACC) {
        const float s = red[0][tid] + red[1][tid] + red[2][tid] + red[3][tid];
        ws[((size_t)b * CHUNKS + blockIdx.x) * NACC + tid] = s;  // no atomics
    }
}

// ---------------------------------------------------------------------------
// Kernel 2: reduce the 64 per-chunk partials, then 9x9 solve w/ 3 RHS.
// Parallel elimination (R1, -3.8us vs serial t==0 version):
//   - chunk-sum: 72 threads in parallel,
//   - elimination: 108 threads own one M[i][j] element; per pivot step
//     {t0 pivot-scan -> 12-thread row swap -> 9-thread multiplier calc ->
//      108-thread rank-1 update}, barriers between phases.
//   - back-substitution: 3 RHS on 3 parallel threads.
// One block per batch. Output S is (B,3,9).
// ---------------------------------------------------------------------------
__global__ __launch_bounds__(128)
void solve_kernel(const float* __restrict__ ws, float* __restrict__ out)
{
    __shared__ float sums[NACC];
    __shared__ float M[9][12];
    __shared__ float fs[9];
    __shared__ int piv_s;
    const int b = blockIdx.x;
    const int t = threadIdx.x;

    // parallel reduction of the 64 per-chunk partials
    if (t < NACC) {
        float s = 0.0f;
        const float* p = ws + (size_t)b * CHUNKS * NACC + t;
#pragma unroll
        for (int c = 0; c < CHUNKS; ++c) s += p[(size_t)c * NACC];
        sums[t] = s;
    }
    __syncthreads();

    // scatter into the 9x12 augmented system, one element per thread
    const int i  = t / 12;
    const int j  = t % 12;
    const bool on = (t < 108);
    if (on) {
        float v;
        if (j < 9) {
            const int lo = (i < j) ? i : j;
            const int hi = (i < j) ? j : i;
            const int k  = lo * 9 - lo * (lo - 1) / 2 + (hi - lo);
            v = sums[k];                      // symmetric AtA
        } else {
            v = sums[45 + (j - 9) * 9 + i];   // Atb, RHS c = j-9
        }
        M[i][j] = v;
    }
    __syncthreads();

    // forward elimination with partial pivoting, parallel over elements
    for (int kk = 0; kk < 9; ++kk) {
        if (t == 0) {
            int piv = kk;
            float best = fabsf(M[kk][kk]);
            for (int r = kk + 1; r < 9; ++r) {
                const float av = fabsf(M[r][kk]);
                if (av > best) { best = av; piv = r; }
            }
            piv_s = piv;
        }
        __syncthreads();
        const int piv = piv_s;
        if (piv != kk && t < 12) {
            const float tmp = M[kk][t];
            M[kk][t] = M[piv][t];
            M[piv][t] = tmp;
        }
        __syncthreads();
        if (t > kk && t < 9) fs[t] = M[t][kk] / M[kk][kk];
        __syncthreads();
        if (on && i > kk) M[i][j] -= fs[i] * M[kk][j];
        __syncthreads();
    }

    // back substitution: 3 RHS in parallel (one thread each)
    if (t < 3) {
        float sol[9];
        for (int kk = 8; kk >= 0; --kk) {
            float v = M[kk][9 + t];
            for (int jj = kk + 1; jj < 9; ++jj) v -= M[kk][jj] * sol[jj];
            sol[kk] = v / M[kk][kk];
        }
        for (int kk = 0; kk < 9; ++kk)
            out[(b * 3 + t) * 9 + kk] = sol[kk];
    }
}

extern "C" void kernel_launch(void* const* d_in, const int* in_sizes, int n_in,
                              void* d_out, int out_size, void* d_ws, size_t ws_size,
                              hipStream_t stream) {
    const float* img = (const float*)d_in[0];   // input_img  (8,3,512,512)
    const float* dep = (const float*)d_in[1];   // depth_target (8,1,512,512)
    const float* alb = (const float*)d_in[2];   // albedo (8,3,512,512)
    float* out = (float*)d_out;                 // S (8,3,9)
    float* ws  = (float*)d_ws;                  // 8*64*72 partial floats

    dim3 grid(CHUNKS, NB);
    accum_kernel<<<grid, 256, 0, stream>>>(img, dep, alb, ws);
    solve_kernel<<<NB, 128, 0, stream>>>(ws, out);
}